// Round 7
// baseline (109.546 us; speedup 1.0000x reference)
//
#include <hip/hip_runtime.h>

#define NB 4
#define NC 8
#define NLOC 524288        // H*W*D
#define TOPN 512
#define POST 100
#define NBIN 8192          // fallback histogram bins
#define SLOTS 256          // gather blocks per image
#define SLOTW 128          // key slots per gather block
#define KEYSPAN (SLOTS*SLOTW)   // 32768 slots/image
#define FB_CAP 16384
#define SCAP 1024          // survivor capacity for rank-count
#define KPT 32             // keys per thread in select (1024*32 = KEYSPAN)
#define LCAP 256           // per-block LDS staging in gather
#define NMS_THR 0.6f
#define CAND_THR 0.05f
#define SPEC_THR 0.5f      // speculative threshold (> CAND_THR; implies cls_raw > 0)

typedef unsigned long long ull;

// ---------------- workspace layout (no memset needed: fully rewritten each call) ----------------
// [0, 4096)        cnt_arr : NB*SLOTS u32 (plain stores every call)
// [4096, 8192)     ovf_arr : NB*SLOTS u32 (plain stores every call)
// [8192, 1056768)  keys    : NB*KEYSPAN u64 (slots beyond cnt are stale -> masked by cnt)
#define OFF_CNT  0
#define OFF_OVF  4096
#define OFF_KEYS 8192

__device__ __forceinline__ float sigmoidf_(float x) {
    return 1.0f / (1.0f + __expf(-x));
}

// ---------------- Pass 1: streaming gather, slot-per-block output ----------------
__global__ __launch_bounds__(256) void gather_spec(const float* __restrict__ cls,
                                                   const float* __restrict__ ctr,
                                                   ull* __restrict__ keys,
                                                   unsigned int* __restrict__ cnt_arr,
                                                   unsigned int* __restrict__ ovf_arr) {
    __shared__ ull lkeys[LCAP];
    __shared__ unsigned int lcnt;
    const int b = blockIdx.y;
    if (threadIdx.x == 0) lcnt = 0;
    __syncthreads();

    const int n0 = (blockIdx.x * blockDim.x + threadIdx.x) * 8;
    const float4* cvp = (const float4*)(ctr + (size_t)b * NLOC + n0);
    const float4 cv0 = cvp[0], cv1 = cvp[1];
    float4 cl0[NC], cl1[NC];
    #pragma unroll
    for (int c = 0; c < NC; ++c) {
        const float4* p = (const float4*)(cls + ((size_t)b * NC + c) * NLOC + n0);
        cl0[c] = p[0];
        cl1[c] = p[1];
    }

    #pragma unroll
    for (int h = 0; h < 2; ++h) {
        const float4 cv = h ? cv1 : cv0;
        #pragma unroll
        for (int j = 0; j < 4; ++j) {
            bool any = false;
            #pragma unroll
            for (int c = 0; c < NC; ++c) {
                const float x = h ? ((const float*)&cl1[c])[j] : ((const float*)&cl0[c])[j];
                any |= (x > 0.0f);
            }
            if (any) {
                const float sc = sigmoidf_(((const float*)&cv)[j]);
                #pragma unroll
                for (int c = 0; c < NC; ++c) {
                    const float x = h ? ((const float*)&cl1[c])[j] : ((const float*)&cl0[c])[j];
                    if (x > 0.0f) {
                        const float p = sigmoidf_(x) * sc;
                        if (p > SPEC_THR) {
                            const unsigned pos = atomicAdd(&lcnt, 1u);
                            if (pos < LCAP) {
                                const unsigned flat = (unsigned)((n0 + h * 4 + j) * NC + c);
                                lkeys[pos] = ((ull)__float_as_uint(p) << 32) | (unsigned)(~flat);
                            }
                        }
                    }
                }
            }
        }
    }
    __syncthreads();
    const unsigned m = lcnt;
    const unsigned stored = (m > (unsigned)SLOTW) ? (unsigned)SLOTW : m;
    ull* kb = keys + ((size_t)b * SLOTS + blockIdx.x) * SLOTW;
    for (unsigned i = threadIdx.x; i < stored; i += blockDim.x) kb[i] = lkeys[i];
    if (threadIdx.x == 0) {
        cnt_arr[b * SLOTS + blockIdx.x] = stored;
        ovf_arr[b * SLOTS + blockIdx.x] = (m > (unsigned)SLOTW) ? 1u : 0u;
    }
}

// ---------------- Pass 2: exact fallback rebuild (tiny early-exit; ~never runs) ----------------
__global__ __launch_bounds__(1024) void fallback_kernel(const float* __restrict__ cls,
                                                        const float* __restrict__ ctr,
                                                        ull* __restrict__ keys,
                                                        unsigned int* __restrict__ cnt_arr,
                                                        unsigned int* __restrict__ ovf_arr) {
    __shared__ unsigned red[32];
    __shared__ int bad_s;
    __shared__ unsigned hist[NBIN];
    __shared__ unsigned cut_s, lpos;
    const int b = blockIdx.x, t = threadIdx.x;

    unsigned c = 0, o = 0;
    if (t < SLOTS) { c = cnt_arr[b * SLOTS + t]; o = ovf_arr[b * SLOTS + t]; }
    #pragma unroll
    for (int d = 32; d >= 1; d >>= 1) { c += __shfl_down(c, d); o |= __shfl_down(o, d); }
    if ((t & 63) == 0 && t < SLOTS) { red[t >> 6] = c; red[16 + (t >> 6)] = o; }
    __syncthreads();
    if (t == 0) {
        const unsigned tot = red[0] + red[1] + red[2] + red[3];
        const unsigned ov = red[16] | red[17] | red[18] | red[19];
        bad_s = (tot < (unsigned)TOPN) || (ov != 0u);
    }
    __syncthreads();
    if (!bad_s) return;

    // exact rebuild: hist -> cutoff bin -> regather dense
    for (int i = t; i < NBIN; i += 1024) hist[i] = 0;
    if (t == 0) lpos = 0;
    __syncthreads();
    for (int n = t; n < NLOC; n += 1024) {
        const float scv = sigmoidf_(ctr[(size_t)b * NLOC + n]);
        #pragma unroll
        for (int cc = 0; cc < NC; ++cc) {
            const float x = cls[((size_t)b * NC + cc) * NLOC + n];
            if (x > -2.9444390f) {                      // sigmoid(x) > 0.05 pre-gate
                const float s = sigmoidf_(x);
                if (s > CAND_THR) atomicAdd(&hist[__float_as_uint(s * scv) >> 17], 1u);
            }
        }
    }
    __syncthreads();
    if (t == 0) {
        unsigned cum = 0; unsigned bin = 0;
        for (int i = NBIN - 1; i >= 0; --i) {
            cum += hist[i];
            if (cum >= (unsigned)TOPN) { bin = (unsigned)i; break; }
        }
        cut_s = bin;
    }
    __syncthreads();
    const unsigned cb = cut_s;
    for (int n = t; n < NLOC; n += 1024) {
        const float scv = sigmoidf_(ctr[(size_t)b * NLOC + n]);
        #pragma unroll
        for (int cc = 0; cc < NC; ++cc) {
            const float x = cls[((size_t)b * NC + cc) * NLOC + n];
            if (x > -2.9444390f) {
                const float s = sigmoidf_(x);
                if (s > CAND_THR) {
                    const unsigned bits = __float_as_uint(s * scv);
                    if ((bits >> 17) >= cb) {
                        const unsigned pos = atomicAdd(&lpos, 1u);
                        if (pos < (unsigned)FB_CAP)
                            keys[(size_t)b * KEYSPAN + pos] =
                                ((ull)bits << 32) | (unsigned)(~(unsigned)(n * NC + cc));
                    }
                }
            }
        }
    }
    __syncthreads();
    const int M_fb = (int)((lpos < (unsigned)FB_CAP) ? lpos : (unsigned)FB_CAP);
    if (t < SLOTS) {
        int rem = M_fb - t * SLOTW;
        rem = (rem < 0) ? 0 : ((rem > SLOTW) ? SLOTW : rem);
        cnt_arr[b * SLOTS + t] = (unsigned)rem;
        ovf_arr[b * SLOTS + t] = 0u;
    }
}

__device__ __forceinline__ float iou3d_(const float* a, const float* bx) {
    const float ix = fminf(a[3], bx[3]) - fmaxf(a[0], bx[0]);
    const float iy = fminf(a[4], bx[4]) - fmaxf(a[1], bx[1]);
    const float iz = fminf(a[5], bx[5]) - fmaxf(a[2], bx[2]);
    const float inter = fmaxf(ix, 0.0f) * fmaxf(iy, 0.0f) * fmaxf(iz, 0.0f);
    const float v0 = fmaxf(a[3] - a[0], 0.0f) * fmaxf(a[4] - a[1], 0.0f) * fmaxf(a[5] - a[2], 0.0f);
    const float v1 = fmaxf(bx[3] - bx[0], 0.0f) * fmaxf(bx[4] - bx[1], 0.0f) * fmaxf(bx[5] - bx[2], 0.0f);
    return inter / (v0 + v1 - inter + 1e-9f);
}

// ---------------- Pass 3: select (binary-search cutoff) + decode + NMS + emit ----------------
__global__ __launch_bounds__(1024) void select_nms_kernel(const ull* __restrict__ keys,
                                                          const unsigned int* __restrict__ cnt_arr,
                                                          const float* __restrict__ loc,
                                                          const float* __restrict__ box,
                                                          float* __restrict__ out) {
    __shared__ union { ull surv[SCAP]; int clist[NC][TOPN]; } u;   // 16KB
    __shared__ ull tk[TOPN];
    __shared__ float sd[TOPN * 6];
    __shared__ float ss[TOPN];
    __shared__ int scl[TOPN];
    __shared__ int keep[TOPN];
    __shared__ float cbox[NC][SLOTW][6];
    __shared__ int wcnt[NC];
    __shared__ unsigned lcnt256[SLOTS];
    __shared__ unsigned wred[32];
    __shared__ unsigned scnt;

    const int b = blockIdx.x, t = threadIdx.x;
    const int lane = t & 63, wid = t >> 6;

    if (t < SLOTS) lcnt256[t] = cnt_arr[b * SLOTS + t];
    __syncthreads();

    // load 32 keys/thread, coalesced; mask stale slots to 0
    const ull* kb = keys + (size_t)b * KEYSPAN;
    ull kv[KPT];
    #pragma unroll
    for (int j = 0; j < KPT; ++j) {
        const int g = j * 1024 + t;
        const ull v = kb[g];
        kv[j] = (((unsigned)g & (SLOTW - 1)) < lcnt256[g >> 7]) ? v : 0ull;
    }

    // binary search: smallest x with count(hi > x) < TOPN
    unsigned lo = 0u, hb = 0x7F800000u;
    int it = 0;
    while (lo < hb) {
        const unsigned mid = (lo + hb) >> 1;
        unsigned c = 0;
        #pragma unroll
        for (int j = 0; j < KPT; ++j) c += ((unsigned)(kv[j] >> 32) > mid) ? 1u : 0u;
        #pragma unroll
        for (int d = 32; d >= 1; d >>= 1) c += __shfl_down(c, d);
        if (lane == 0) wred[(it & 1) * 16 + wid] = c;
        __syncthreads();
        unsigned tot = 0;
        #pragma unroll
        for (int w = 0; w < 16; ++w) tot += wred[(it & 1) * 16 + w];
        if (tot < (unsigned)TOPN) hb = mid; else lo = mid + 1;
        ++it;
    }
    const unsigned T = lo;

    // compact hi >= max(T,1) (wave-aggregated)
    if (t == 0) scnt = 0;
    __syncthreads();
    const unsigned CT = (T == 0u) ? 1u : T;
    #pragma unroll
    for (int j = 0; j < KPT; ++j) {
        const bool pred = ((unsigned)(kv[j] >> 32) >= CT);
        const ull mv = __ballot(pred);
        unsigned base = 0;
        if (lane == 0 && mv) base = atomicAdd(&scnt, (unsigned)__popcll(mv));
        base = __shfl(base, 0);
        if (pred) {
            const unsigned pos = base + (unsigned)__popcll(mv & ((1ull << lane) - 1ull));
            if (pos < (unsigned)SCAP) u.surv[pos] = kv[j];
        }
    }
    __syncthreads();

    // pathological tie refinement (block-uniform, ~never taken)
    if (scnt > (unsigned)SCAP) {
        unsigned c = 0;
        #pragma unroll
        for (int j = 0; j < KPT; ++j) c += ((unsigned)(kv[j] >> 32) > T) ? 1u : 0u;
        #pragma unroll
        for (int d = 32; d >= 1; d >>= 1) c += __shfl_down(c, d);
        if (lane == 0) wred[wid] = c;
        __syncthreads();
        unsigned gt = 0;
        #pragma unroll
        for (int w = 0; w < 16; ++w) gt += wred[w];
        const unsigned need = (unsigned)TOPN - gt;
        __syncthreads();
        unsigned lo2 = 0u, hb2 = 0xFFFFFFFFu;
        int it2 = 0;
        while (lo2 < hb2) {
            const unsigned mid = lo2 + ((hb2 - lo2) >> 1);
            unsigned cc = 0;
            #pragma unroll
            for (int j = 0; j < KPT; ++j)
                cc += (((unsigned)(kv[j] >> 32) == T) && ((unsigned)kv[j] > mid)) ? 1u : 0u;
            #pragma unroll
            for (int d = 32; d >= 1; d >>= 1) cc += __shfl_down(cc, d);
            if (lane == 0) wred[(it2 & 1) * 16 + wid] = cc;
            __syncthreads();
            unsigned tot2 = 0;
            #pragma unroll
            for (int w = 0; w < 16; ++w) tot2 += wred[(it2 & 1) * 16 + w];
            if (tot2 < need) hb2 = mid; else lo2 = mid + 1;
            ++it2;
        }
        const unsigned L = lo2;
        if (t == 0) scnt = 0;
        __syncthreads();
        #pragma unroll
        for (int j = 0; j < KPT; ++j) {
            const unsigned hw = (unsigned)(kv[j] >> 32);
            const bool pred = (hw > T) || ((hw == T) && ((unsigned)kv[j] >= L));
            const ull mv = __ballot(pred);
            unsigned base = 0;
            if (lane == 0 && mv) base = atomicAdd(&scnt, (unsigned)__popcll(mv));
            base = __shfl(base, 0);
            if (pred) {
                const unsigned pos = base + (unsigned)__popcll(mv & ((1ull << lane) - 1ull));
                if (pos < (unsigned)SCAP) u.surv[pos] = kv[j];
            }
        }
        __syncthreads();
    }

    // exact rank-count among survivors -> tk (sorted desc)
    const int S = (int)((scnt < (unsigned)SCAP) ? scnt : (unsigned)SCAP);
    if (t < TOPN) tk[t] = 0;
    __syncthreads();
    for (int i = t; i < S; i += 1024) {
        const ull ke = u.surv[i];
        int r = 0;
        for (int j = 0; j < S; ++j) r += (u.surv[j] > ke) ? 1 : 0;
        if (r < TOPN) tk[r] = ke;
    }
    __syncthreads();

    // decode (t < 512)
    if (t < TOPN) {
        const ull k = tk[t];
        const unsigned bits = (unsigned)(k >> 32);
        const float val = __uint_as_float(bits);
        int valid = (val > 0.0f) ? 1 : 0;
        const unsigned flat = ~(unsigned)(k & 0xffffffffu);
        int n = 0, c = 0;
        if (valid) { n = (int)(flat >> 3); c = (int)(flat & 7u); }
        const float lx = loc[n * 3 + 0], ly = loc[n * 3 + 1], lz = loc[n * 3 + 2];
        const float* bp = box + (size_t)b * 6 * NLOC + n;
        const float b0 = bp[0];
        const float b1 = bp[(size_t)NLOC];
        const float b2 = bp[2 * (size_t)NLOC];
        const float b3 = bp[3 * (size_t)NLOC];
        const float b4 = bp[4 * (size_t)NLOC];
        const float b5 = bp[5 * (size_t)NLOC];
        const float d0 = fminf(fmaxf(lx - b0, 0.0f), 255.0f);
        const float d1 = fminf(fmaxf(ly - b1, 0.0f), 255.0f);
        const float d2 = fminf(fmaxf(lz - b2, 0.0f), 63.0f);
        const float d3 = fminf(fmaxf(lx + b3, 0.0f), 255.0f);
        const float d4 = fminf(fmaxf(ly + b4, 0.0f), 255.0f);
        const float d5 = fminf(fmaxf(lz + b5, 0.0f), 63.0f);
        if (d3 - d0 < 0.0f || d4 - d1 < 0.0f || d5 - d2 < 0.0f) valid = 0;
        sd[t * 6 + 0] = d0; sd[t * 6 + 1] = d1; sd[t * 6 + 2] = d2;
        sd[t * 6 + 3] = d3; sd[t * 6 + 4] = d4; sd[t * 6 + 5] = d5;
        ss[t] = (val > 0.0f) ? sqrtf(val) : 0.0f;
        scl[t] = c + 1;
        keep[t] = valid;
    }
    __syncthreads();

    // per-class NMS (wave w = class w+1)
    if (t < TOPN) {
        const int w = wid;
        const int myclass = w + 1;
        int cnt = 0;
        for (int j0 = 0; j0 < TOPN; j0 += 64) {
            const int j = j0 + lane;
            const bool pred = (scl[j] == myclass) && (keep[j] != 0);
            const ull m = __ballot(pred);
            if (pred) {
                const int pos = cnt + __popcll(m & ((1ull << lane) - 1ull));
                u.clist[w][pos] = j;
                if (pos < SLOTW) {
                    #pragma unroll
                    for (int q = 0; q < 6; ++q) cbox[w][pos][q] = sd[j * 6 + q];
                }
            }
            cnt += __popcll(m);
        }
        __threadfence_block();

        if (cnt <= SLOTW) {
            const bool h0 = (lane < cnt), h1 = (lane + 64 < cnt);
            float A0[6], A1[6];
            #pragma unroll
            for (int q = 0; q < 6; ++q) {
                A0[q] = h0 ? cbox[w][lane][q] : 0.0f;
                A1[q] = h1 ? cbox[w][lane + 64][q] : 0.0f;
            }
            ull s0 = 0, s1lo = 0, s1hi = 0;
            for (int i = 0; i < cnt; ++i) {
                float pb[6];
                #pragma unroll
                for (int q = 0; q < 6; ++q) pb[q] = cbox[w][i][q];
                if (i < 64) {
                    if (h0 && lane > i && iou3d_(A0, pb) > NMS_THR) s0 |= 1ull << i;
                    if (h1 && iou3d_(A1, pb) > NMS_THR) s1lo |= 1ull << i;
                } else {
                    if (h1 && (i - 64) < lane && iou3d_(A1, pb) > NMS_THR) s1hi |= 1ull << (i - 64);
                }
            }
            bool a0 = h0, a1 = h1;
            ull m0 = __ballot(a0), m1 = __ballot(a1);
            for (int i = 0; i < cnt; ++i) {
                const bool alive_i = (i < 64) ? ((m0 >> i) & 1ull) : ((m1 >> (i - 64)) & 1ull);
                if (!alive_i) continue;
                if (a0 && i < 64 && ((s0 >> i) & 1ull)) a0 = false;
                if (a1) {
                    const bool sb = (i < 64) ? ((s1lo >> i) & 1ull) : ((s1hi >> (i - 64)) & 1ull);
                    if (sb) a1 = false;
                }
                m0 = __ballot(a0); m1 = __ballot(a1);
            }
            if (h0 && !a0) keep[u.clist[w][lane]] = 0;
            if (h1 && !a1) keep[u.clist[w][lane + 64]] = 0;
        } else {
            volatile int* vkeep = keep;
            for (int i = 0; i < cnt; ++i) {
                const int gi = u.clist[w][i];
                if (!vkeep[gi]) continue;
                float pb[6];
                #pragma unroll
                for (int q = 0; q < 6; ++q) pb[q] = sd[gi * 6 + q];
                for (int e = i + 1 + lane; e < cnt; e += 64) {
                    const int gj = u.clist[w][e];
                    if (vkeep[gj]) {
                        float cb_[6];
                        #pragma unroll
                        for (int q = 0; q < 6; ++q) cb_[q] = sd[gj * 6 + q];
                        if (iou3d_(cb_, pb) > NMS_THR) vkeep[gj] = 0;
                    }
                }
                __threadfence_block();
            }
        }
    }
    __syncthreads();

    // rank survivors in position order, emit top-100
    if (t < TOPN) {
        const ull km = __ballot(keep[t] != 0);
        if (lane == 0) wcnt[wid] = __popcll(km);
    }
    __syncthreads();
    if (t < TOPN) {
        const int w = wid;
        const ull km = __ballot(keep[t] != 0);
        int before = 0, total = 0;
        #pragma unroll
        for (int w2 = 0; w2 < NC; ++w2) {
            total += wcnt[w2];
            if (w2 < w) before += wcnt[w2];
        }
        const int myrank = before + __popcll(km & ((1ull << lane) - 1ull));

        float* fbox = out;                       // (B,100,6)
        float* fscore = out + NB * POST * 6;     // (B,100)
        float* flabel = out + NB * POST * 7;     // (B,100)
        float* fvalid = out + NB * POST * 8;     // (B,100)

        if (keep[t] && myrank < POST) {
            #pragma unroll
            for (int k = 0; k < 6; ++k) fbox[(b * POST + myrank) * 6 + k] = sd[t * 6 + k];
            fscore[b * POST + myrank] = ss[t];
            flabel[b * POST + myrank] = (float)scl[t];
            fvalid[b * POST + myrank] = 1.0f;
        }
        const int tc = (total < POST) ? total : POST;
        if (t >= tc && t < POST) {
            #pragma unroll
            for (int k = 0; k < 6; ++k) fbox[(b * POST + t) * 6 + k] = 0.0f;
            fscore[b * POST + t] = 0.0f;
            flabel[b * POST + t] = 0.0f;
            fvalid[b * POST + t] = 0.0f;
        }
    }
}

extern "C" void kernel_launch(void* const* d_in, const int* in_sizes, int n_in,
                              void* d_out, int out_size, void* d_ws, size_t ws_size,
                              hipStream_t stream) {
    const float* location = (const float*)d_in[0];
    const float* cls_pred = (const float*)d_in[1];
    const float* box_pred = (const float*)d_in[2];
    const float* ctr_pred = (const float*)d_in[3];

    char* ws = (char*)d_ws;
    unsigned int* cnt_arr = (unsigned int*)(ws + OFF_CNT);
    unsigned int* ovf_arr = (unsigned int*)(ws + OFF_OVF);
    ull*          keys    = (ull*)(ws + OFF_KEYS);

    gather_spec<<<dim3(SLOTS, NB), 256, 0, stream>>>(cls_pred, ctr_pred, keys, cnt_arr, ovf_arr);
    fallback_kernel<<<NB, 1024, 0, stream>>>(cls_pred, ctr_pred, keys, cnt_arr, ovf_arr);
    select_nms_kernel<<<NB, 1024, 0, stream>>>(keys, cnt_arr, location, box_pred, (float*)d_out);
}

// Round 8
// 98.613 us; speedup vs baseline: 1.1109x; 1.1109x over previous
//
#include <hip/hip_runtime.h>

#define NB 4
#define NC 8
#define NLOC 524288        // H*W*D
#define TOPN 512
#define POST 100
#define NBIN 8192          // fallback histogram bins
#define SELBINS 4096       // select histogram bins over score bits (0.5..1.0)
#define SCAP 2048          // survivor capacity for rank-count
#define WPI 2048           // waves per image (512 blocks x 4 waves)
#define SLOTW 16           // key slots per wave
#define KEYSPAN (WPI*SLOTW)   // 32768 slots/image
#define FB_CAP 16384
#define NMS_THR 0.6f
#define CAND_THR 0.05f

typedef unsigned long long ull;

// ---------------- workspace layout (fully rewritten each call; no memset) ----------------
// [0, 32768)        cnt_arr : NB*WPI u32
// [32768, 65536)    ovf_arr : NB*WPI u32
// [65536, 1114112)  keys    : NB*KEYSPAN u64 (slots beyond cnt are stale -> masked)
#define OFF_CNT  0
#define OFF_OVF  32768
#define OFF_KEYS 65536

__device__ __forceinline__ float sigmoidf_(float x) {
    return 1.0f / (1.0f + __expf(-x));
}

// ---------------- Pass 1: streaming gather — no LDS, no atomics, no barriers ----------------
__global__ __launch_bounds__(256) void gather_spec(const float* __restrict__ cls,
                                                   const float* __restrict__ ctr,
                                                   ull* __restrict__ keys,
                                                   unsigned int* __restrict__ cnt_arr,
                                                   unsigned int* __restrict__ ovf_arr) {
    const int b = blockIdx.y;
    const int lane = threadIdx.x & 63, wid = threadIdx.x >> 6;
    const int n0 = (blockIdx.x * 256 + threadIdx.x) * 4;

    const float4 cv = *(const float4*)(ctr + (size_t)b * NLOC + n0);
    float4 cl[NC];
    #pragma unroll
    for (int c = 0; c < NC; ++c)
        cl[c] = *(const float4*)(cls + ((size_t)b * NC + c) * NLOC + n0);

    unsigned hm = 0;
    #pragma unroll
    for (int j = 0; j < 4; ++j)
        #pragma unroll
        for (int c = 0; c < NC; ++c)
            if (((const float*)&cl[c])[j] > 0.0f) hm |= 1u << (j * 8 + c);

    ull k0 = 0, k1 = 0, k2 = 0, k3 = 0;
    int kc = 0;
    if (hm) {                                  // ~4.7% of lanes
        #pragma unroll
        for (int j = 0; j < 4; ++j) {
            if ((hm >> (j * 8)) & 0xffu) {
                const float sc = sigmoidf_(((const float*)&cv)[j]);
                #pragma unroll
                for (int c = 0; c < NC; ++c) {
                    if ((hm >> (j * 8 + c)) & 1u) {
                        const float p = sigmoidf_(((const float*)&cl[c])[j]) * sc;
                        if (p > 0.5f) {        // implies candid (0.05) and top-512 superset
                            const unsigned flat = (unsigned)((n0 + j) * NC + c);
                            const ull key = ((ull)__float_as_uint(p) << 32) | (unsigned)(~flat);
                            if (kc == 0) k0 = key;
                            else if (kc == 1) k1 = key;
                            else if (kc == 2) k2 = key;
                            else if (kc == 3) k3 = key;
                            ++kc;
                        }
                    }
                }
            }
        }
    }
    // wave-level prefix placement via 4 ballots (kc in [0,4] stored; >4 flags fallback)
    const ull m1 = __ballot(kc >= 1), m2 = __ballot(kc >= 2);
    const ull m3 = __ballot(kc >= 3), m4 = __ballot(kc >= 4);
    const ull lt = (1ull << lane) - 1ull;
    const unsigned pos = (unsigned)(__popcll(m1 & lt) + __popcll(m2 & lt) +
                                    __popcll(m3 & lt) + __popcll(m4 & lt));
    const unsigned tot = (unsigned)(__popcll(m1) + __popcll(m2) + __popcll(m3) + __popcll(m4));
    const int wgid = blockIdx.x * 4 + wid;
    ull* kb = keys + ((size_t)b * WPI + wgid) * SLOTW;
    const int sc_ = (kc > 4) ? 4 : kc;
    if (sc_ >= 1 && pos + 0 < SLOTW) kb[pos + 0] = k0;
    if (sc_ >= 2 && pos + 1 < SLOTW) kb[pos + 1] = k1;
    if (sc_ >= 3 && pos + 2 < SLOTW) kb[pos + 2] = k2;
    if (sc_ >= 4 && pos + 3 < SLOTW) kb[pos + 3] = k3;
    const ull mo = __ballot(kc > 4);
    if (lane == 0) {
        cnt_arr[b * WPI + wgid] = (tot > (unsigned)SLOTW) ? (unsigned)SLOTW : tot;
        ovf_arr[b * WPI + wgid] = ((tot > (unsigned)SLOTW) || mo) ? 1u : 0u;
    }
}

__device__ __forceinline__ float iou3d_(const float* a, const float* bx) {
    const float ix = fminf(a[3], bx[3]) - fmaxf(a[0], bx[0]);
    const float iy = fminf(a[4], bx[4]) - fmaxf(a[1], bx[1]);
    const float iz = fminf(a[5], bx[5]) - fmaxf(a[2], bx[2]);
    const float inter = fmaxf(ix, 0.0f) * fmaxf(iy, 0.0f) * fmaxf(iz, 0.0f);
    const float v0 = fmaxf(a[3] - a[0], 0.0f) * fmaxf(a[4] - a[1], 0.0f) * fmaxf(a[5] - a[2], 0.0f);
    const float v1 = fmaxf(bx[3] - bx[0], 0.0f) * fmaxf(bx[4] - bx[1], 0.0f) * fmaxf(bx[5] - bx[2], 0.0f);
    return inter / (v0 + v1 - inter + 1e-9f);
}

// ---------------- Pass 2: fused check + select + decode + NMS + emit (1 block/image) ----------------
__global__ __launch_bounds__(1024) void select_nms_kernel(const float* __restrict__ cls,
                                                          const float* __restrict__ ctr,
                                                          ull* __restrict__ keys,
                                                          const unsigned int* __restrict__ cnt_arr,
                                                          const unsigned int* __restrict__ ovf_arr,
                                                          const float* __restrict__ loc,
                                                          const float* __restrict__ box,
                                                          float* __restrict__ out) {
    __shared__ union SU {
        struct { unsigned int cnt[WPI]; unsigned int hist[SELBINS]; ull surv[SCAP]; } sel; // 40KB
        struct { unsigned int fhist[NBIN]; unsigned int cnt2[WPI]; } fb;                   // 40KB
        struct { float sd[TOPN * 6]; float ss[TOPN]; int scl[TOPN];
                 int keep[TOPN]; int clist[NC][TOPN];
                 float cbox[NC][128][6]; int wcnt[NC]; } nms;                              // ~58KB
    } u;
    __shared__ ull tk[TOPN];
    __shared__ unsigned wredc[16], wredo[16];
    __shared__ unsigned scnt, lpos;
    __shared__ int cut_s, bad_s;

    const int b = blockIdx.x, t = threadIdx.x;
    const int lane = t & 63, wid = t >> 6;
    const ull* kb = keys + (size_t)b * KEYSPAN;

    // ---------- phase A: load per-wave counts, reduce total & overflow ----------
    unsigned myc = 0, myo = 0;
    unsigned c0v, c1v;
    {
        c0v = cnt_arr[b * WPI + t];
        c1v = cnt_arr[b * WPI + t + 1024];
        myc = c0v + c1v;
        myo = ovf_arr[b * WPI + t] | ovf_arr[b * WPI + t + 1024];
    }
    #pragma unroll
    for (int d = 32; d >= 1; d >>= 1) { myc += __shfl_down(myc, d); myo |= __shfl_down(myo, d); }
    if (lane == 0) { wredc[wid] = myc; wredo[wid] = myo; }
    __syncthreads();
    if (t == 0) {
        unsigned tot = 0, ov = 0;
        #pragma unroll
        for (int w = 0; w < 16; ++w) { tot += wredc[w]; ov |= wredo[w]; }
        bad_s = (tot < (unsigned)TOPN) || (ov != 0u);
        lpos = 0;
    }
    __syncthreads();
    const bool bad = (bad_s != 0);

    if (!bad) {
        u.sel.cnt[t] = c0v;
        u.sel.cnt[t + 1024] = c1v;
    } else {
        // ---------- exact fallback rebuild (block-uniform; ~never runs) ----------
        for (int i = t; i < NBIN; i += 1024) u.fb.fhist[i] = 0;
        __syncthreads();
        for (int n = t; n < NLOC; n += 1024) {
            const float scv = sigmoidf_(ctr[(size_t)b * NLOC + n]);
            #pragma unroll
            for (int cc = 0; cc < NC; ++cc) {
                const float x = cls[((size_t)b * NC + cc) * NLOC + n];
                if (x > -2.9444390f) {                 // sigmoid(x) > 0.05 pre-gate
                    const float s = sigmoidf_(x);
                    if (s > CAND_THR) atomicAdd(&u.fb.fhist[__float_as_uint(s * scv) >> 17], 1u);
                }
            }
        }
        __syncthreads();
        if (t == 0) {
            unsigned cum = 0; int bin = 0;
            for (int i = NBIN - 1; i >= 0; --i) {
                cum += u.fb.fhist[i];
                if (cum >= (unsigned)TOPN) { bin = i; break; }
            }
            cut_s = bin;
        }
        __syncthreads();
        const unsigned cb2 = (unsigned)cut_s;
        for (int n = t; n < NLOC; n += 1024) {
            const float scv = sigmoidf_(ctr[(size_t)b * NLOC + n]);
            #pragma unroll
            for (int cc = 0; cc < NC; ++cc) {
                const float x = cls[((size_t)b * NC + cc) * NLOC + n];
                if (x > -2.9444390f) {
                    const float s = sigmoidf_(x);
                    if (s > CAND_THR) {
                        const unsigned bits = __float_as_uint(s * scv);
                        if ((bits >> 17) >= cb2) {
                            const unsigned pos = atomicAdd(&lpos, 1u);
                            if (pos < (unsigned)FB_CAP)
                                keys[(size_t)b * KEYSPAN + pos] =
                                    ((ull)bits << 32) | (unsigned)(~(unsigned)(n * NC + cc));
                        }
                    }
                }
            }
        }
        __threadfence();
        __syncthreads();
        const int M_fb = (int)((lpos < (unsigned)FB_CAP) ? lpos : (unsigned)FB_CAP);
        for (int i = 0; i < 2; ++i) {
            const int s = t + i * 1024;
            int rem = M_fb - s * SLOTW;
            rem = (rem < 0) ? 0 : ((rem > SLOTW) ? SLOTW : rem);
            u.fb.cnt2[s] = (unsigned)rem;     // cnt2 aliases sel.cnt region? -> copy below
        }
    }
    __syncthreads();
    // unify cnt view for select phase (fb.cnt2 sits after fhist; move into sel.cnt)
    if (bad) {
        unsigned a0 = u.fb.cnt2[t], a1 = u.fb.cnt2[t + 1024];
        __syncthreads();
        u.sel.cnt[t] = a0; u.sel.cnt[t + 1024] = a1;
    }
    __syncthreads();

    // ---------- phase B: histogram over key score bits (stream keys, masked) ----------
    for (int i = t; i < SELBINS; i += 1024) u.sel.hist[i] = 0;
    if (t == 0) scnt = 0;
    if (t < TOPN) tk[t] = 0;
    __syncthreads();
    for (int it = 0; it < KEYSPAN / 1024; ++it) {
        const int g = it * 1024 + t;
        const bool valid = ((unsigned)g & (SLOTW - 1)) < u.sel.cnt[g >> 4];
        const ull k = kb[g];
        if (valid) {
            const unsigned hi = (unsigned)(k >> 32);
            const int off = (int)hi - 0x3F000000;
            int bin = (off < 0) ? 0 : (off >> 11);
            if (bin > SELBINS - 1) bin = SELBINS - 1;
            atomicAdd(&u.sel.hist[bin], 1u);
        }
    }
    __syncthreads();

    // ---------- phase C: cutoff bin via wave-0 suffix scan ----------
    if (t < 64) {
        unsigned s = 0;
        #pragma unroll 8
        for (int i = 0; i < 64; ++i)
            s += u.sel.hist[t * 64 + ((i + t) & 63)];
        unsigned suf = s;
        #pragma unroll
        for (int d = 1; d < 64; d <<= 1) {
            const unsigned o = __shfl_down(suf, d);
            suf += (t + d < 64) ? o : 0u;
        }
        const ull mask = __ballot(suf >= TOPN);
        unsigned nxt = __shfl_down(suf, 1);
        if (t == 63) nxt = 0;
        if (mask == 0ull) {
            if (t == 0) cut_s = 0;
        } else {
            const int L = 63 - __builtin_clzll(mask);
            if (t == L) {
                unsigned cum = nxt;
                int c = L * 64;
                for (int i = 63; i >= 0; --i) {
                    cum += u.sel.hist[L * 64 + i];
                    if (cum >= TOPN) { c = L * 64 + i; break; }
                }
                cut_s = c;
            }
        }
    }
    __syncthreads();

    // ---------- phase D: compact survivors (re-read keys, L2-hot; wave-agg) ----------
    const int cb = cut_s;
    for (int it = 0; it < KEYSPAN / 1024; ++it) {
        const int g = it * 1024 + t;
        const bool valid = ((unsigned)g & (SLOTW - 1)) < u.sel.cnt[g >> 4];
        const ull k = kb[g];
        bool pred = false;
        if (valid) {
            const unsigned hi = (unsigned)(k >> 32);
            const int off = (int)hi - 0x3F000000;
            int bin = (off < 0) ? 0 : (off >> 11);
            if (bin > SELBINS - 1) bin = SELBINS - 1;
            pred = (bin >= cb);
        }
        const ull mv = __ballot(pred);
        unsigned base = 0;
        if (lane == 0 && mv) base = atomicAdd(&scnt, (unsigned)__popcll(mv));
        base = __shfl(base, 0);
        if (pred) {
            const unsigned pos = base + (unsigned)__popcll(mv & ((1ull << lane) - 1ull));
            if (pos < (unsigned)SCAP) u.sel.surv[pos] = k;
        }
    }
    __syncthreads();

    // ---------- phase E: exact rank-count among survivors -> tk (sorted desc) ----------
    const int S = (int)((scnt < (unsigned)SCAP) ? scnt : (unsigned)SCAP);
    for (int i = t; i < S; i += 1024) {
        const ull ke = u.sel.surv[i];
        int r = 0;
        for (int j = 0; j < S; ++j) r += (u.sel.surv[j] > ke) ? 1 : 0;
        if (r < TOPN) tk[r] = ke;
    }
    __syncthreads();

    // ---------- phase F: decode (t < 512) ----------
    if (t < TOPN) {
        const ull k = tk[t];
        const unsigned bits = (unsigned)(k >> 32);
        const float val = __uint_as_float(bits);
        int valid = (val > 0.0f) ? 1 : 0;
        const unsigned flat = ~(unsigned)(k & 0xffffffffu);
        int n = 0, c = 0;
        if (valid) { n = (int)(flat >> 3); c = (int)(flat & 7u); }
        const float lx = loc[n * 3 + 0], ly = loc[n * 3 + 1], lz = loc[n * 3 + 2];
        const float* bp = box + (size_t)b * 6 * NLOC + n;
        const float b0 = bp[0];
        const float b1 = bp[(size_t)NLOC];
        const float b2 = bp[2 * (size_t)NLOC];
        const float b3 = bp[3 * (size_t)NLOC];
        const float b4 = bp[4 * (size_t)NLOC];
        const float b5 = bp[5 * (size_t)NLOC];
        const float d0 = fminf(fmaxf(lx - b0, 0.0f), 255.0f);
        const float d1 = fminf(fmaxf(ly - b1, 0.0f), 255.0f);
        const float d2 = fminf(fmaxf(lz - b2, 0.0f), 63.0f);
        const float d3 = fminf(fmaxf(lx + b3, 0.0f), 255.0f);
        const float d4 = fminf(fmaxf(ly + b4, 0.0f), 255.0f);
        const float d5 = fminf(fmaxf(lz + b5, 0.0f), 63.0f);
        if (d3 - d0 < 0.0f || d4 - d1 < 0.0f || d5 - d2 < 0.0f) valid = 0;
        u.nms.sd[t * 6 + 0] = d0; u.nms.sd[t * 6 + 1] = d1; u.nms.sd[t * 6 + 2] = d2;
        u.nms.sd[t * 6 + 3] = d3; u.nms.sd[t * 6 + 4] = d4; u.nms.sd[t * 6 + 5] = d5;
        u.nms.ss[t] = (val > 0.0f) ? sqrtf(val) : 0.0f;
        u.nms.scl[t] = c + 1;
        u.nms.keep[t] = valid;
    }
    __syncthreads();

    // ---------- phase G: per-class NMS (wave w = class w+1) ----------
    if (t < TOPN) {
        const int w = wid;
        const int myclass = w + 1;
        int cnt = 0;
        for (int j0 = 0; j0 < TOPN; j0 += 64) {
            const int j = j0 + lane;
            const bool pred = (u.nms.scl[j] == myclass) && (u.nms.keep[j] != 0);
            const ull m = __ballot(pred);
            if (pred) {
                const int pos = cnt + __popcll(m & ((1ull << lane) - 1ull));
                u.nms.clist[w][pos] = j;
                if (pos < 128) {
                    #pragma unroll
                    for (int q = 0; q < 6; ++q) u.nms.cbox[w][pos][q] = u.nms.sd[j * 6 + q];
                }
            }
            cnt += __popcll(m);
        }
        __threadfence_block();

        if (cnt <= 128) {
            const bool h0 = (lane < cnt), h1 = (lane + 64 < cnt);
            float A0[6], A1[6];
            #pragma unroll
            for (int q = 0; q < 6; ++q) {
                A0[q] = h0 ? u.nms.cbox[w][lane][q] : 0.0f;
                A1[q] = h1 ? u.nms.cbox[w][lane + 64][q] : 0.0f;
            }
            ull s0 = 0, s1lo = 0, s1hi = 0;
            for (int i = 0; i < cnt; ++i) {
                float pb[6];
                #pragma unroll
                for (int q = 0; q < 6; ++q) pb[q] = u.nms.cbox[w][i][q];
                if (i < 64) {
                    if (h0 && lane > i && iou3d_(A0, pb) > NMS_THR) s0 |= 1ull << i;
                    if (h1 && iou3d_(A1, pb) > NMS_THR) s1lo |= 1ull << i;
                } else {
                    if (h1 && (i - 64) < lane && iou3d_(A1, pb) > NMS_THR) s1hi |= 1ull << (i - 64);
                }
            }
            bool a0 = h0, a1 = h1;
            ull m0 = __ballot(a0), m1 = __ballot(a1);
            for (int i = 0; i < cnt; ++i) {
                const bool alive_i = (i < 64) ? ((m0 >> i) & 1ull) : ((m1 >> (i - 64)) & 1ull);
                if (!alive_i) continue;
                if (a0 && i < 64 && ((s0 >> i) & 1ull)) a0 = false;
                if (a1) {
                    const bool sb = (i < 64) ? ((s1lo >> i) & 1ull) : ((s1hi >> (i - 64)) & 1ull);
                    if (sb) a1 = false;
                }
                m0 = __ballot(a0); m1 = __ballot(a1);
            }
            if (h0 && !a0) u.nms.keep[u.nms.clist[w][lane]] = 0;
            if (h1 && !a1) u.nms.keep[u.nms.clist[w][lane + 64]] = 0;
        } else {
            volatile int* vkeep = u.nms.keep;
            for (int i = 0; i < cnt; ++i) {
                const int gi = u.nms.clist[w][i];
                if (!vkeep[gi]) continue;
                float pb[6];
                #pragma unroll
                for (int q = 0; q < 6; ++q) pb[q] = u.nms.sd[gi * 6 + q];
                for (int e = i + 1 + lane; e < cnt; e += 64) {
                    const int gj = u.nms.clist[w][e];
                    if (vkeep[gj]) {
                        float cb_[6];
                        #pragma unroll
                        for (int q = 0; q < 6; ++q) cb_[q] = u.nms.sd[gj * 6 + q];
                        if (iou3d_(cb_, pb) > NMS_THR) vkeep[gj] = 0;
                    }
                }
                __threadfence_block();
            }
        }
    }
    __syncthreads();

    // ---------- phase H: rank survivors in position order, emit top-100 ----------
    if (t < TOPN) {
        const ull km = __ballot(u.nms.keep[t] != 0);
        if (lane == 0) u.nms.wcnt[wid] = __popcll(km);
    }
    __syncthreads();
    if (t < TOPN) {
        const int w = wid;
        const ull km = __ballot(u.nms.keep[t] != 0);
        int before = 0, total = 0;
        #pragma unroll
        for (int w2 = 0; w2 < NC; ++w2) {
            total += u.nms.wcnt[w2];
            if (w2 < w) before += u.nms.wcnt[w2];
        }
        const int myrank = before + __popcll(km & ((1ull << lane) - 1ull));

        float* fbox = out;                       // (B,100,6)
        float* fscore = out + NB * POST * 6;     // (B,100)
        float* flabel = out + NB * POST * 7;     // (B,100)
        float* fvalid = out + NB * POST * 8;     // (B,100)

        if (u.nms.keep[t] && myrank < POST) {
            #pragma unroll
            for (int k = 0; k < 6; ++k) fbox[(b * POST + myrank) * 6 + k] = u.nms.sd[t * 6 + k];
            fscore[b * POST + myrank] = u.nms.ss[t];
            flabel[b * POST + myrank] = (float)u.nms.scl[t];
            fvalid[b * POST + myrank] = 1.0f;
        }
        const int tc = (total < POST) ? total : POST;
        if (t >= tc && t < POST) {
            #pragma unroll
            for (int k = 0; k < 6; ++k) fbox[(b * POST + t) * 6 + k] = 0.0f;
            fscore[b * POST + t] = 0.0f;
            flabel[b * POST + t] = 0.0f;
            fvalid[b * POST + t] = 0.0f;
        }
    }
}

extern "C" void kernel_launch(void* const* d_in, const int* in_sizes, int n_in,
                              void* d_out, int out_size, void* d_ws, size_t ws_size,
                              hipStream_t stream) {
    const float* location = (const float*)d_in[0];
    const float* cls_pred = (const float*)d_in[1];
    const float* box_pred = (const float*)d_in[2];
    const float* ctr_pred = (const float*)d_in[3];

    char* ws = (char*)d_ws;
    unsigned int* cnt_arr = (unsigned int*)(ws + OFF_CNT);
    unsigned int* ovf_arr = (unsigned int*)(ws + OFF_OVF);
    ull*          keys    = (ull*)(ws + OFF_KEYS);

    gather_spec<<<dim3(NLOC / 1024, NB), 256, 0, stream>>>(cls_pred, ctr_pred, keys, cnt_arr, ovf_arr);
    select_nms_kernel<<<NB, 1024, 0, stream>>>(cls_pred, ctr_pred, keys, cnt_arr, ovf_arr,
                                               location, box_pred, (float*)d_out);
}